// Round 1
// baseline (207.946 us; speedup 1.0000x reference)
//
#include <hip/hip_runtime.h>
#include <hip/hip_bf16.h>

// proto_net_loss: h = X@W1; BN(train, per-set batch stats); ReLU; z = h@W2;
// D = ||z1_i||^2 + ||z2_j||^2 - 2*z1_i.z2_j   (8192 x 2048, f32)

#define LAT 512
#define HID 128
#define EPSV 1e-5f

// ---------------- Kernel 1: H = X @ W1  (M x 512)(512 x 128) ----------------
// BM=64, BN=128 (full), BK=16. 256 threads. tx=tid&31 -> cols tx*4; ty=tid>>5 -> rows ty*8.
__global__ __launch_bounds__(256) void k_gemm1(const float* __restrict__ X,
                                               const float* __restrict__ W1,
                                               float* __restrict__ H) {
  __shared__ float As[16][68];   // As[k][m], padded (272B rows: 16B aligned)
  __shared__ float Bs[16][132];  // Bs[k][n], padded (528B rows: 16B aligned)
  const int tid = threadIdx.x;
  const int row0 = blockIdx.x * 64;
  const int tx = tid & 31, ty = tid >> 5;
  float acc[8][4] = {};
  for (int k0 = 0; k0 < LAT; k0 += 16) {
    // A tile: 64 m x 16 k; thread reads float4 at m=tid/4, kk=(tid&3)*4 (coalesced)
    {
      const int m = tid >> 2, kk = (tid & 3) << 2;
      const float4 v = *(const float4*)(X + (size_t)(row0 + m) * LAT + k0 + kk);
      As[kk + 0][m] = v.x; As[kk + 1][m] = v.y;
      As[kk + 2][m] = v.z; As[kk + 3][m] = v.w;
    }
    // B tile: 16 k x 128 n; two float4 per thread
    {
      const int kk = tid >> 5, n = (tid & 31) << 2;
      *(float4*)&Bs[kk][n]     = *(const float4*)(W1 + (size_t)(k0 + kk) * HID + n);
      *(float4*)&Bs[kk + 8][n] = *(const float4*)(W1 + (size_t)(k0 + kk + 8) * HID + n);
    }
    __syncthreads();
#pragma unroll
    for (int kk = 0; kk < 16; ++kk) {
      const float4 alo = *(const float4*)&As[kk][ty * 8];
      const float4 ahi = *(const float4*)&As[kk][ty * 8 + 4];
      const float4 bv  = *(const float4*)&Bs[kk][tx * 4];
      const float a[8] = {alo.x, alo.y, alo.z, alo.w, ahi.x, ahi.y, ahi.z, ahi.w};
      const float b[4] = {bv.x, bv.y, bv.z, bv.w};
#pragma unroll
      for (int j = 0; j < 8; ++j)
#pragma unroll
        for (int l = 0; l < 4; ++l) acc[j][l] = fmaf(a[j], b[l], acc[j][l]);
    }
    __syncthreads();
  }
#pragma unroll
  for (int j = 0; j < 8; ++j) {
    const float4 v = {acc[j][0], acc[j][1], acc[j][2], acc[j][3]};
    *(float4*)(H + (size_t)(row0 + ty * 8 + j) * HID + tx * 4) = v;
  }
}

// ---------------- Kernel 2: per-column partial sums (deterministic 2-stage) ----------------
__global__ __launch_bounds__(256) void k_colstats(const float* __restrict__ H, int n,
                                                  float* __restrict__ partS,
                                                  float* __restrict__ partQ) {
  const int tid = threadIdx.x;
  const int col = tid & 127;
  const int r0 = tid >> 7;             // 0 or 1
  const int rows_per = n / gridDim.x;  // n divisible by grid (8192/64, 2048/64)
  const int rbeg = blockIdx.x * rows_per;
  float s = 0.f, q = 0.f;
  for (int r = rbeg + r0; r < rbeg + rows_per; r += 2) {
    const float v = H[(size_t)r * HID + col];
    s += v; q += v * v;
  }
  __shared__ float ss[256], qq[256];
  ss[tid] = s; qq[tid] = q;
  __syncthreads();
  if (tid < 128) {
    partS[blockIdx.x * HID + tid] = ss[tid] + ss[tid + 128];
    partQ[blockIdx.x * HID + tid] = qq[tid] + qq[tid + 128];
  }
}

// ---------------- Kernel 2b: finalize BN affine (scale/shift per column, per set) ----------------
__global__ __launch_bounds__(256) void k_finalize(const float* __restrict__ pS1,
                                                  const float* __restrict__ pQ1,
                                                  const float* __restrict__ pS2,
                                                  const float* __restrict__ pQ2,
                                                  const float* __restrict__ gamma,
                                                  const float* __restrict__ beta,
                                                  float* __restrict__ sc1, float* __restrict__ sh1,
                                                  float* __restrict__ sc2, float* __restrict__ sh2,
                                                  float n1count, float n2count) {
  const int tid = threadIdx.x;  // 256: [0,128) set1, [128,256) set2
  const int col = tid & 127;
  const float* pS = (tid < 128) ? pS1 : pS2;
  const float* pQ = (tid < 128) ? pQ1 : pQ2;
  const float n = (tid < 128) ? n1count : n2count;
  float s = 0.f, q = 0.f;
  for (int b = 0; b < 64; ++b) { s += pS[b * HID + col]; q += pQ[b * HID + col]; }
  const float mean = s / n;
  const float var = q / n - mean * mean;  // biased var, matches jnp.var
  const float rstd = rsqrtf(var + EPSV);
  const float scale = gamma[col] * rstd;
  const float shift = beta[col] - mean * scale;
  if (tid < 128) { sc1[col] = scale; sh1[col] = shift; }
  else           { sc2[col] = scale; sh2[col] = shift; }
}

// ---------------- Kernel 3: Z = relu(H*sc+sh) @ W2, plus row norms ----------------
__global__ __launch_bounds__(256) void k_gemm2(const float* __restrict__ H,
                                               const float* __restrict__ W2,
                                               const float* __restrict__ sc,
                                               const float* __restrict__ sh,
                                               float* __restrict__ Z,
                                               float* __restrict__ nrm) {
  __shared__ float As[16][68];
  __shared__ float Bs[16][132];
  const int tid = threadIdx.x;
  const int row0 = blockIdx.x * 64;
  const int tx = tid & 31, ty = tid >> 5;
  float acc[8][4] = {};
  for (int k0 = 0; k0 < HID; k0 += 16) {
    {
      const int m = tid >> 2, kk = (tid & 3) << 2;
      const float4 v = *(const float4*)(H + (size_t)(row0 + m) * HID + k0 + kk);
      As[kk + 0][m] = fmaxf(fmaf(v.x, sc[k0 + kk + 0], sh[k0 + kk + 0]), 0.f);
      As[kk + 1][m] = fmaxf(fmaf(v.y, sc[k0 + kk + 1], sh[k0 + kk + 1]), 0.f);
      As[kk + 2][m] = fmaxf(fmaf(v.z, sc[k0 + kk + 2], sh[k0 + kk + 2]), 0.f);
      As[kk + 3][m] = fmaxf(fmaf(v.w, sc[k0 + kk + 3], sh[k0 + kk + 3]), 0.f);
    }
    {
      const int kk = tid >> 5, n = (tid & 31) << 2;
      *(float4*)&Bs[kk][n]     = *(const float4*)(W2 + (size_t)(k0 + kk) * HID + n);
      *(float4*)&Bs[kk + 8][n] = *(const float4*)(W2 + (size_t)(k0 + kk + 8) * HID + n);
    }
    __syncthreads();
#pragma unroll
    for (int kk = 0; kk < 16; ++kk) {
      const float4 alo = *(const float4*)&As[kk][ty * 8];
      const float4 ahi = *(const float4*)&As[kk][ty * 8 + 4];
      const float4 bv  = *(const float4*)&Bs[kk][tx * 4];
      const float a[8] = {alo.x, alo.y, alo.z, alo.w, ahi.x, ahi.y, ahi.z, ahi.w};
      const float b[4] = {bv.x, bv.y, bv.z, bv.w};
#pragma unroll
      for (int j = 0; j < 8; ++j)
#pragma unroll
        for (int l = 0; l < 4; ++l) acc[j][l] = fmaf(a[j], b[l], acc[j][l]);
    }
    __syncthreads();
  }
#pragma unroll
  for (int j = 0; j < 8; ++j) {
    const float4 v = {acc[j][0], acc[j][1], acc[j][2], acc[j][3]};
    *(float4*)(Z + (size_t)(row0 + ty * 8 + j) * HID + tx * 4) = v;
    // row-norm partial: this thread's 4 cols
    float rn = acc[j][0] * acc[j][0] + acc[j][1] * acc[j][1] +
               acc[j][2] * acc[j][2] + acc[j][3] * acc[j][3];
    // reduce across the 32 tx lanes (same ty => contiguous 32-lane group in wave)
#pragma unroll
    for (int m = 16; m >= 1; m >>= 1) rn += __shfl_xor(rn, m, 64);
    if (tx == 0) nrm[row0 + ty * 8 + j] = rn;
  }
}

// ---------------- Kernel 4: D = n1[i] + n2[j] - 2 * Z1 @ Z2^T ----------------
// 64x64 tile, full K=128 staged transposed in LDS (exactly 64 KB -> 2 blocks/CU).
__global__ __launch_bounds__(256) void k_dist(const float* __restrict__ Z1,
                                              const float* __restrict__ Z2,
                                              const float* __restrict__ n1,
                                              const float* __restrict__ n2,
                                              float* __restrict__ D, int NYc) {
  __shared__ float As[128][64];  // As[k][m] (Z1 tile, transposed)
  __shared__ float Bs[128][64];  // Bs[k][n] (Z2 tile, transposed)
  const int tid = threadIdx.x;
  const int rowB = blockIdx.y * 64;
  const int colB = blockIdx.x * 64;
  {
    const int m = tid >> 2;            // 0..63
    const int kb = (tid & 3) << 2;     // 0,4,8,12
#pragma unroll
    for (int i = 0; i < 8; ++i) {
      const int k = kb + 16 * i;
      const float4 a = *(const float4*)(Z1 + (size_t)(rowB + m) * HID + k);
      As[k + 0][m] = a.x; As[k + 1][m] = a.y; As[k + 2][m] = a.z; As[k + 3][m] = a.w;
      const float4 b = *(const float4*)(Z2 + (size_t)(colB + m) * HID + k);
      Bs[k + 0][m] = b.x; Bs[k + 1][m] = b.y; Bs[k + 2][m] = b.z; Bs[k + 3][m] = b.w;
    }
  }
  __syncthreads();
  const int u = tid >> 4;   // 0..15 -> rows u*4..u*4+3
  const int p = tid & 15;   // 0..15 -> cols p*4..p*4+3
  float acc[4][4] = {};
#pragma unroll 8
  for (int k = 0; k < 128; ++k) {
    const float4 a = *(const float4*)&As[k][u * 4];
    const float4 b = *(const float4*)&Bs[k][p * 4];
    const float av[4] = {a.x, a.y, a.z, a.w};
    const float bv[4] = {b.x, b.y, b.z, b.w};
#pragma unroll
    for (int i = 0; i < 4; ++i)
#pragma unroll
      for (int l = 0; l < 4; ++l) acc[i][l] = fmaf(av[i], bv[l], acc[i][l]);
  }
  const float4 nb = *(const float4*)(n2 + colB + p * 4);
  const float nbv[4] = {nb.x, nb.y, nb.z, nb.w};
#pragma unroll
  for (int i = 0; i < 4; ++i) {
    const float na = n1[rowB + u * 4 + i];
    float4 o;
    o.x = na + nbv[0] - 2.f * acc[i][0];
    o.y = na + nbv[1] - 2.f * acc[i][1];
    o.z = na + nbv[2] - 2.f * acc[i][2];
    o.w = na + nbv[3] - 2.f * acc[i][3];
    *(float4*)(D + (size_t)(rowB + u * 4 + i) * NYc + colB + p * 4) = o;
  }
}

extern "C" void kernel_launch(void* const* d_in, const int* in_sizes, int n_in,
                              void* d_out, int out_size, void* d_ws, size_t ws_size,
                              hipStream_t stream) {
  const float* variations = (const float*)d_in[0];
  const float* exemplar   = (const float*)d_in[1];
  const float* w1         = (const float*)d_in[2];
  const float* gamma      = (const float*)d_in[3];
  const float* beta       = (const float*)d_in[4];
  const float* w2         = (const float*)d_in[5];
  float* D = (float*)d_out;

  const int nx = in_sizes[0] / LAT;  // 8192
  const int ny = in_sizes[1] / LAT;  // 2048

  // workspace layout (floats)
  float* ws = (float*)d_ws;
  float* H1 = ws;                      // nx*128
  float* H2 = H1 + (size_t)nx * HID;   // ny*128
  float* Z1 = H2 + (size_t)ny * HID;   // nx*128
  float* Z2 = Z1 + (size_t)nx * HID;   // ny*128
  float* pS1 = Z2 + (size_t)ny * HID;  // 64*128
  float* pQ1 = pS1 + 64 * HID;
  float* pS2 = pQ1 + 64 * HID;
  float* pQ2 = pS2 + 64 * HID;
  float* sc1 = pQ2 + 64 * HID;         // 128 each
  float* sh1 = sc1 + HID;
  float* sc2 = sh1 + HID;
  float* sh2 = sc2 + HID;
  float* n1v = sh2 + HID;              // nx
  float* n2v = n1v + nx;               // ny

  k_gemm1<<<nx / 64, 256, 0, stream>>>(variations, w1, H1);
  k_gemm1<<<ny / 64, 256, 0, stream>>>(exemplar, w1, H2);
  k_colstats<<<64, 256, 0, stream>>>(H1, nx, pS1, pQ1);
  k_colstats<<<64, 256, 0, stream>>>(H2, ny, pS2, pQ2);
  k_finalize<<<1, 256, 0, stream>>>(pS1, pQ1, pS2, pQ2, gamma, beta,
                                    sc1, sh1, sc2, sh2, (float)nx, (float)ny);
  k_gemm2<<<nx / 64, 256, 0, stream>>>(H1, w2, sc1, sh1, Z1, n1v);
  k_gemm2<<<ny / 64, 256, 0, stream>>>(H2, w2, sc2, sh2, Z2, n2v);
  dim3 dgrid(ny / 64, nx / 64);
  k_dist<<<dgrid, 256, 0, stream>>>(Z1, Z2, n1v, n2v, D, ny);
}

// Round 2
// 143.159 us; speedup vs baseline: 1.4526x; 1.4526x over previous
//
#include <hip/hip_runtime.h>
#include <hip/hip_bf16.h>

// proto_net_loss: h = X@W1; BN(train stats); ReLU; z = h@W2 (bf16);
// D = ||z1_i||^2 + ||z2_j||^2 - 2*z1_i.z2_j  via bf16 MFMA. (8192 x 2048 f32 out)

#define LAT 512
#define HID 128
#define EPSV 1e-5f

typedef __attribute__((ext_vector_type(8))) short bf16x8;
typedef __attribute__((ext_vector_type(4))) float f32x4;

__device__ inline unsigned short f2bf(float x) {
  unsigned int u = __builtin_bit_cast(unsigned int, x);
  unsigned int r = (u + 0x7fffu + ((u >> 16) & 1u)) >> 16;
  return (unsigned short)r;
}

// ---------------- Kernel 1: H = X @ W1 (BM=32, BN=128, BK=16) + fused column partial stats ----
__global__ __launch_bounds__(256) void k_gemm1(const float* __restrict__ X,
                                               const float* __restrict__ W1,
                                               float* __restrict__ H,
                                               float* __restrict__ partS,
                                               float* __restrict__ partQ) {
  __shared__ float As[16][36];    // As[k][m], 144B rows (16B aligned)
  __shared__ float Bs[16][132];   // Bs[k][n], 528B rows
  __shared__ float sS[8][132], sQ[8][132];
  const int tid = threadIdx.x;
  const int row0 = blockIdx.x * 32;
  const int tx = tid & 31, ty = tid >> 5;   // cols tx*4, rows ty*4
  float acc[4][4] = {};
  for (int k0 = 0; k0 < LAT; k0 += 16) {
    {  // A tile 32m x 16k: float2 per thread
      const int m = tid >> 3, kk = (tid & 7) << 1;
      const float2 v = *(const float2*)(X + (size_t)(row0 + m) * LAT + k0 + kk);
      As[kk + 0][m] = v.x; As[kk + 1][m] = v.y;
    }
    {  // B tile 16k x 128n: two float4 per thread
      const int kk = tid >> 5, n = (tid & 31) << 2;
      *(float4*)&Bs[kk][n]     = *(const float4*)(W1 + (size_t)(k0 + kk) * HID + n);
      *(float4*)&Bs[kk + 8][n] = *(const float4*)(W1 + (size_t)(k0 + kk + 8) * HID + n);
    }
    __syncthreads();
#pragma unroll
    for (int kk = 0; kk < 16; ++kk) {
      const float4 av = *(const float4*)&As[kk][ty * 4];
      const float4 bv = *(const float4*)&Bs[kk][tx * 4];
      const float a[4] = {av.x, av.y, av.z, av.w};
      const float b[4] = {bv.x, bv.y, bv.z, bv.w};
#pragma unroll
      for (int j = 0; j < 4; ++j)
#pragma unroll
        for (int l = 0; l < 4; ++l) acc[j][l] = fmaf(a[j], b[l], acc[j][l]);
    }
    __syncthreads();
  }
#pragma unroll
  for (int j = 0; j < 4; ++j) {
    const float4 v = {acc[j][0], acc[j][1], acc[j][2], acc[j][3]};
    *(float4*)(H + (size_t)(row0 + ty * 4 + j) * HID + tx * 4) = v;
  }
  // fused per-block column stats (sum, sumsq over the 32 rows)
  float s[4], q[4];
#pragma unroll
  for (int l = 0; l < 4; ++l) {
    s[l] = acc[0][l] + acc[1][l] + acc[2][l] + acc[3][l];
    q[l] = acc[0][l] * acc[0][l] + acc[1][l] * acc[1][l] +
           acc[2][l] * acc[2][l] + acc[3][l] * acc[3][l];
  }
#pragma unroll
  for (int l = 0; l < 4; ++l) { sS[ty][tx * 4 + l] = s[l]; sQ[ty][tx * 4 + l] = q[l]; }
  __syncthreads();
  if (tid < 128) {
    const int col = tid;
    float ss = 0.f, qq = 0.f;
#pragma unroll
    for (int r = 0; r < 8; ++r) { ss += sS[r][col]; qq += sQ[r][col]; }
    partS[blockIdx.x * HID + col] = ss;
    partQ[blockIdx.x * HID + col] = qq;
  }
}

// ---------------- Kernel 2: finalize BN affine per set ----------------
__global__ __launch_bounds__(256) void k_finalize(const float* __restrict__ pS1,
                                                  const float* __restrict__ pQ1,
                                                  const float* __restrict__ pS2,
                                                  const float* __restrict__ pQ2,
                                                  const float* __restrict__ gamma,
                                                  const float* __restrict__ beta,
                                                  float* __restrict__ sc1, float* __restrict__ sh1,
                                                  float* __restrict__ sc2, float* __restrict__ sh2,
                                                  int nb1, int nb2, float n1count, float n2count) {
  const int tid = threadIdx.x;
  const int col = tid & 127;
  const float* pS = (tid < 128) ? pS1 : pS2;
  const float* pQ = (tid < 128) ? pQ1 : pQ2;
  const int nb = (tid < 128) ? nb1 : nb2;
  const float n = (tid < 128) ? n1count : n2count;
  float s0 = 0.f, s1 = 0.f, q0 = 0.f, q1 = 0.f;
  for (int b = 0; b < nb; b += 2) {
    s0 += pS[(size_t)b * HID + col];       q0 += pQ[(size_t)b * HID + col];
    s1 += pS[(size_t)(b + 1) * HID + col]; q1 += pQ[(size_t)(b + 1) * HID + col];
  }
  const float s = s0 + s1, q = q0 + q1;
  const float mean = s / n;
  const float var = q / n - mean * mean;
  const float rstd = rsqrtf(var + EPSV);
  const float scale = gamma[col] * rstd;
  const float shift = beta[col] - mean * scale;
  if (tid < 128) { sc1[col] = scale; sh1[col] = shift; }
  else           { sc2[col] = scale; sh2[col] = shift; }
}

// ---------------- Kernel 3: Zb(bf16) = relu(H*sc+sh) @ W2, plus f32 row norms ----------------
__global__ __launch_bounds__(256) void k_gemm2(const float* __restrict__ H,
                                               const float* __restrict__ W2,
                                               const float* __restrict__ sc,
                                               const float* __restrict__ sh,
                                               unsigned short* __restrict__ Zb,
                                               float* __restrict__ nrm) {
  __shared__ float As[16][36];
  __shared__ float Bs[16][132];
  const int tid = threadIdx.x;
  const int row0 = blockIdx.x * 32;
  const int tx = tid & 31, ty = tid >> 5;
  float acc[4][4] = {};
  for (int k0 = 0; k0 < HID; k0 += 16) {
    {
      const int m = tid >> 3, kk = (tid & 7) << 1;
      const float2 v = *(const float2*)(H + (size_t)(row0 + m) * HID + k0 + kk);
      As[kk + 0][m] = fmaxf(fmaf(v.x, sc[k0 + kk + 0], sh[k0 + kk + 0]), 0.f);
      As[kk + 1][m] = fmaxf(fmaf(v.y, sc[k0 + kk + 1], sh[k0 + kk + 1]), 0.f);
    }
    {
      const int kk = tid >> 5, n = (tid & 31) << 2;
      *(float4*)&Bs[kk][n]     = *(const float4*)(W2 + (size_t)(k0 + kk) * HID + n);
      *(float4*)&Bs[kk + 8][n] = *(const float4*)(W2 + (size_t)(k0 + kk + 8) * HID + n);
    }
    __syncthreads();
#pragma unroll
    for (int kk = 0; kk < 16; ++kk) {
      const float4 av = *(const float4*)&As[kk][ty * 4];
      const float4 bv = *(const float4*)&Bs[kk][tx * 4];
      const float a[4] = {av.x, av.y, av.z, av.w};
      const float b[4] = {bv.x, bv.y, bv.z, bv.w};
#pragma unroll
      for (int j = 0; j < 4; ++j)
#pragma unroll
        for (int l = 0; l < 4; ++l) acc[j][l] = fmaf(a[j], b[l], acc[j][l]);
    }
    __syncthreads();
  }
#pragma unroll
  for (int j = 0; j < 4; ++j) {
    const int row = row0 + ty * 4 + j;
    ushort4 z;
    z.x = f2bf(acc[j][0]); z.y = f2bf(acc[j][1]);
    z.z = f2bf(acc[j][2]); z.w = f2bf(acc[j][3]);
    *(ushort4*)(Zb + (size_t)row * HID + tx * 4) = z;
    float rn = acc[j][0] * acc[j][0] + acc[j][1] * acc[j][1] +
               acc[j][2] * acc[j][2] + acc[j][3] * acc[j][3];
#pragma unroll
    for (int m = 16; m >= 1; m >>= 1) rn += __shfl_xor(rn, m, 64);
    if (tx == 0) nrm[row] = rn;
  }
}

// ---------------- Kernel 4: D = n1[i] + n2[j] - 2 * Z1b @ Z2b^T (bf16 MFMA) ----------------
// 128x128 block tile, 4 waves 2x2, 64x64 per wave, K=128 (4 mfma k-steps), no LDS.
__global__ __launch_bounds__(256) void k_dist(const unsigned short* __restrict__ Z1b,
                                              const unsigned short* __restrict__ Z2b,
                                              const float* __restrict__ n1,
                                              const float* __restrict__ n2,
                                              float* __restrict__ D, int NY) {
  const int tid = threadIdx.x;
  const int wid = tid >> 6, lane = tid & 63;
  const int wr = wid >> 1, wc = wid & 1;
  const int rowB = blockIdx.y * 128 + wr * 64;
  const int colB = blockIdx.x * 128 + wc * 64;
  const int l15 = lane & 15;
  const int lk = (lane >> 4) * 8;
  const unsigned short* Arow = Z1b + (size_t)(rowB + l15) * HID + lk;
  const unsigned short* Brow = Z2b + (size_t)(colB + l15) * HID + lk;
  f32x4 acc[4][4];
#pragma unroll
  for (int i = 0; i < 4; ++i)
#pragma unroll
    for (int j = 0; j < 4; ++j) acc[i][j] = (f32x4){0.f, 0.f, 0.f, 0.f};
#pragma unroll
  for (int s = 0; s < 4; ++s) {
    bf16x8 a[4], b[4];
#pragma unroll
    for (int i = 0; i < 4; ++i) a[i] = *(const bf16x8*)(Arow + (size_t)i * 16 * HID + s * 32);
#pragma unroll
    for (int j = 0; j < 4; ++j) b[j] = *(const bf16x8*)(Brow + (size_t)j * 16 * HID + s * 32);
#pragma unroll
    for (int i = 0; i < 4; ++i)
#pragma unroll
      for (int j = 0; j < 4; ++j)
        acc[i][j] = __builtin_amdgcn_mfma_f32_16x16x32_bf16(a[i], b[j], acc[i][j], 0, 0, 0);
  }
  // epilogue: D[row][col] = n1[row] + n2[col] - 2*dot
  float nb[4];
#pragma unroll
  for (int j = 0; j < 4; ++j) nb[j] = n2[colB + j * 16 + l15];
  const int crow0 = (lane >> 4) * 4;
#pragma unroll
  for (int i = 0; i < 4; ++i) {
#pragma unroll
    for (int r = 0; r < 4; ++r) {
      const int row = rowB + i * 16 + crow0 + r;
      const float na = n1[row];
      float* drow = D + (size_t)row * NY + colB + l15;
#pragma unroll
      for (int j = 0; j < 4; ++j)
        drow[j * 16] = na + nb[j] - 2.f * acc[i][j][r];
    }
  }
}

extern "C" void kernel_launch(void* const* d_in, const int* in_sizes, int n_in,
                              void* d_out, int out_size, void* d_ws, size_t ws_size,
                              hipStream_t stream) {
  const float* variations = (const float*)d_in[0];
  const float* exemplar   = (const float*)d_in[1];
  const float* w1         = (const float*)d_in[2];
  const float* gamma      = (const float*)d_in[3];
  const float* beta       = (const float*)d_in[4];
  const float* w2         = (const float*)d_in[5];
  float* D = (float*)d_out;

  const int nx = in_sizes[0] / LAT;  // 8192
  const int ny = in_sizes[1] / LAT;  // 2048
  const int nb1 = nx / 32, nb2 = ny / 32;  // 256, 64

  float* ws = (float*)d_ws;
  float* H1 = ws;                        // nx*128
  float* H2 = H1 + (size_t)nx * HID;     // ny*128
  float* pS1 = H2 + (size_t)ny * HID;    // nb1*128
  float* pQ1 = pS1 + (size_t)nb1 * HID;
  float* pS2 = pQ1 + (size_t)nb1 * HID;  // nb2*128
  float* pQ2 = pS2 + (size_t)nb2 * HID;
  float* sc1 = pQ2 + (size_t)nb2 * HID;  // 128 each
  float* sh1 = sc1 + HID;
  float* sc2 = sh1 + HID;
  float* sh2 = sc2 + HID;
  float* n1v = sh2 + HID;                // nx
  float* n2v = n1v + nx;                 // ny
  unsigned short* Z1b = (unsigned short*)(n2v + ny);        // nx*128 bf16
  unsigned short* Z2b = Z1b + (size_t)nx * HID;             // ny*128 bf16

  k_gemm1<<<nb1, 256, 0, stream>>>(variations, w1, H1, pS1, pQ1);
  k_gemm1<<<nb2, 256, 0, stream>>>(exemplar, w1, H2, pS2, pQ2);
  k_finalize<<<1, 256, 0, stream>>>(pS1, pQ1, pS2, pQ2, gamma, beta,
                                    sc1, sh1, sc2, sh2, nb1, nb2, (float)nx, (float)ny);
  k_gemm2<<<nb1, 256, 0, stream>>>(H1, w2, sc1, sh1, Z1b, n1v);
  k_gemm2<<<nb2, 256, 0, stream>>>(H2, w2, sc2, sh2, Z2b, n2v);
  dim3 dgrid(ny / 128, nx / 128);
  k_dist<<<dgrid, 256, 0, stream>>>(Z1b, Z2b, n1v, n2v, D, ny);
}

// Round 3
// 85.195 us; speedup vs baseline: 2.4408x; 1.6804x over previous
//
#include <hip/hip_runtime.h>
#include <hip/hip_bf16.h>

// proto_net_loss, all-MFMA version:
//  prep:   W1T/W2T = bf16 transposed weights (L2-resident)
//  gemm1:  H(bf16) = X @ W1 via MFMA, fused per-block BN partial stats, both sets
//  final:  BN scale/shift per set
//  gemm2:  Z(bf16) = relu(H*sc+sh) @ W2 via MFMA + f32 row norms, both sets
//  dist:   D = n1[i] + n2[j] - 2 * Z1 @ Z2^T via MFMA

#define LAT 512
#define HID 128
#define EPSV 1e-5f

typedef __attribute__((ext_vector_type(8))) short bf16x8;
typedef __attribute__((ext_vector_type(4))) float f32x4;

__device__ inline unsigned short f2bf(float x) {  // RTNE
  unsigned int u = __builtin_bit_cast(unsigned int, x);
  return (unsigned short)((u + 0x7fffu + ((u >> 16) & 1u)) >> 16);
}
__device__ inline float bf2f(unsigned short h) {
  unsigned int u = ((unsigned int)h) << 16;
  return __builtin_bit_cast(float, u);
}

// ---------------- prep: transpose weights to bf16 ----------------
__global__ __launch_bounds__(256) void k_prep(const float* __restrict__ W1,
                                              const float* __restrict__ W2,
                                              unsigned short* __restrict__ W1T,
                                              unsigned short* __restrict__ W2T) {
  const int t = blockIdx.x * 256 + threadIdx.x;
  if (t < LAT * HID) {
    const int n = t >> 9, k = t & 511;  // W1T[n][k] = W1[k][n]
    W1T[t] = f2bf(W1[(size_t)k * HID + n]);
  } else {
    const int t2 = t - LAT * HID;
    if (t2 < HID * HID) {
      const int n = t2 >> 7, k = t2 & 127;
      W2T[t2] = f2bf(W2[(size_t)k * HID + n]);
    }
  }
}

// ---------------- gemm1: H = X @ W1 (MFMA, no LDS staging) + partial stats ----------------
// 4 waves/block, each wave: 16 rows x 128 cols, K=512. grid = (nx+ny)/64.
__global__ __launch_bounds__(256) void k_gemm1(
    const float* __restrict__ X1, const float* __restrict__ X2, int nx,
    const unsigned short* __restrict__ W1T, unsigned short* __restrict__ H,
    float* __restrict__ pS1, float* __restrict__ pQ1,
    float* __restrict__ pS2, float* __restrict__ pQ2, int nb1) {
  __shared__ float sS[16][HID], sQ[16][HID];
  const int tid = threadIdx.x, wid = tid >> 6, lane = tid & 63;
  const int l15 = lane & 15, lq = lane >> 4, lk8 = lq * 8;
  const int browBase = (int)blockIdx.x * 64;
  const int row0 = browBase + wid * 16;
  const float* X = (browBase < nx) ? X1 : X2;
  const int xrow = (browBase < nx) ? row0 : row0 - nx;
  const float* xptr = X + (size_t)(xrow + l15) * LAT + lk8;
  f32x4 acc[8];
#pragma unroll
  for (int f = 0; f < 8; ++f) acc[f] = (f32x4){0.f, 0.f, 0.f, 0.f};

#pragma unroll
  for (int kb = 0; kb < LAT; kb += 128) {
    float4 xv[4][2];
#pragma unroll
    for (int s = 0; s < 4; ++s) {
      xv[s][0] = *(const float4*)(xptr + kb + s * 32);
      xv[s][1] = *(const float4*)(xptr + kb + s * 32 + 4);
    }
#pragma unroll
    for (int s = 0; s < 4; ++s) {
      const float vv[8] = {xv[s][0].x, xv[s][0].y, xv[s][0].z, xv[s][0].w,
                           xv[s][1].x, xv[s][1].y, xv[s][1].z, xv[s][1].w};
      bf16x8 bfr;
#pragma unroll
      for (int i = 0; i < 8; ++i) bfr[i] = (short)f2bf(vv[i]);
      const int k = kb + s * 32 + lk8;
#pragma unroll
      for (int f = 0; f < 8; ++f) {
        const bf16x8 afr = *(const bf16x8*)(W1T + (size_t)(f * 16 + l15) * LAT + k);
        acc[f] = __builtin_amdgcn_mfma_f32_16x16x32_bf16(afr, bfr, acc[f], 0, 0, 0);
      }
    }
  }
  // store H row-major bf16: lane holds H[m=row0+l15][n=f*16+lq*4+r]
#pragma unroll
  for (int f = 0; f < 8; ++f) {
    ushort4 hz = {f2bf(acc[f][0]), f2bf(acc[f][1]), f2bf(acc[f][2]), f2bf(acc[f][3])};
    *(ushort4*)(H + (size_t)(row0 + l15) * HID + f * 16 + lq * 4) = hz;
  }
  // partial stats: sum over m of h and h^2 per column n.
  // 2-stage shfl (xor 1,2) then LDS rows [wid*4 + l15/4].
#pragma unroll
  for (int f = 0; f < 8; ++f) {
    f32x4 s = acc[f];
    f32x4 q = acc[f] * acc[f];
#pragma unroll
    for (int r = 0; r < 4; ++r) {
      s[r] += __shfl_xor(s[r], 1, 64);
      q[r] += __shfl_xor(q[r], 1, 64);
      s[r] += __shfl_xor(s[r], 2, 64);
      q[r] += __shfl_xor(q[r], 2, 64);
    }
    if ((l15 & 3) == 0) {
      *(f32x4*)&sS[wid * 4 + (l15 >> 2)][f * 16 + lq * 4] = s;
      *(f32x4*)&sQ[wid * 4 + (l15 >> 2)][f * 16 + lq * 4] = q;
    }
  }
  __syncthreads();
  if (tid < HID) {
    float s = 0.f, q = 0.f;
#pragma unroll
    for (int r = 0; r < 16; ++r) { s += sS[r][tid]; q += sQ[r][tid]; }
    float* pS = (blockIdx.x < (unsigned)nb1) ? pS1 + (size_t)blockIdx.x * HID
                                             : pS2 + (size_t)(blockIdx.x - nb1) * HID;
    float* pQ = (blockIdx.x < (unsigned)nb1) ? pQ1 + (size_t)blockIdx.x * HID
                                             : pQ2 + (size_t)(blockIdx.x - nb1) * HID;
    pS[tid] = s;
    pQ[tid] = q;
  }
}

// ---------------- finalize BN affine per set ----------------
__global__ __launch_bounds__(256) void k_finalize(const float* __restrict__ pS1,
                                                  const float* __restrict__ pQ1,
                                                  const float* __restrict__ pS2,
                                                  const float* __restrict__ pQ2,
                                                  const float* __restrict__ gamma,
                                                  const float* __restrict__ beta,
                                                  float* __restrict__ sc1, float* __restrict__ sh1,
                                                  float* __restrict__ sc2, float* __restrict__ sh2,
                                                  int nb1, int nb2, float n1count, float n2count) {
  const int tid = threadIdx.x;
  const int col = tid & 127;
  const float* pS = (tid < 128) ? pS1 : pS2;
  const float* pQ = (tid < 128) ? pQ1 : pQ2;
  const int nb = (tid < 128) ? nb1 : nb2;
  const float n = (tid < 128) ? n1count : n2count;
  float s0 = 0.f, s1 = 0.f, q0 = 0.f, q1 = 0.f;
  for (int b = 0; b < nb; b += 2) {
    s0 += pS[(size_t)b * HID + col];       q0 += pQ[(size_t)b * HID + col];
    s1 += pS[(size_t)(b + 1) * HID + col]; q1 += pQ[(size_t)(b + 1) * HID + col];
  }
  const float s = s0 + s1, q = q0 + q1;
  const float mean = s / n;
  const float var = q / n - mean * mean;
  const float rstd = rsqrtf(var + EPSV);
  const float scale = gamma[col] * rstd;
  const float shift = beta[col] - mean * scale;
  if (tid < 128) { sc1[col] = scale; sh1[col] = shift; }
  else           { sc2[col] = scale; sh2[col] = shift; }
}

// ---------------- gemm2: Z(bf16) = relu(H*sc+sh) @ W2 + f32 row norms ----------------
__global__ __launch_bounds__(256) void k_gemm2(
    const unsigned short* __restrict__ H, int nx,
    const unsigned short* __restrict__ W2T,
    const float* __restrict__ sc1, const float* __restrict__ sh1,
    const float* __restrict__ sc2, const float* __restrict__ sh2,
    unsigned short* __restrict__ Z, float* __restrict__ nrm) {
  const int tid = threadIdx.x, wid = tid >> 6, lane = tid & 63;
  const int l15 = lane & 15, lq = lane >> 4, lk8 = lq * 8;
  const int row0 = (int)blockIdx.x * 64 + wid * 16;
  const bool set1 = row0 < nx;
  const float* sc = set1 ? sc1 : sc2;
  const float* sh = set1 ? sh1 : sh2;
  const unsigned short* hptr = H + (size_t)(row0 + l15) * HID + lk8;
  f32x4 acc[8];
#pragma unroll
  for (int f = 0; f < 8; ++f) acc[f] = (f32x4){0.f, 0.f, 0.f, 0.f};
#pragma unroll
  for (int s = 0; s < 4; ++s) {
    const int k = s * 32 + lk8;
    const bf16x8 hv = *(const bf16x8*)(hptr + s * 32);
    const float4 c0 = *(const float4*)(sc + k);
    const float4 c1 = *(const float4*)(sc + k + 4);
    const float4 d0 = *(const float4*)(sh + k);
    const float4 d1 = *(const float4*)(sh + k + 4);
    const float cc[8] = {c0.x, c0.y, c0.z, c0.w, c1.x, c1.y, c1.z, c1.w};
    const float dd[8] = {d0.x, d0.y, d0.z, d0.w, d1.x, d1.y, d1.z, d1.w};
    bf16x8 bfr;
#pragma unroll
    for (int i = 0; i < 8; ++i) {
      const float a = fmaxf(fmaf(bf2f((unsigned short)hv[i]), cc[i], dd[i]), 0.f);
      bfr[i] = (short)f2bf(a);
    }
#pragma unroll
    for (int f = 0; f < 8; ++f) {
      const bf16x8 afr = *(const bf16x8*)(W2T + (size_t)(f * 16 + l15) * HID + k);
      acc[f] = __builtin_amdgcn_mfma_f32_16x16x32_bf16(afr, bfr, acc[f], 0, 0, 0);
    }
  }
  float rn = 0.f;
#pragma unroll
  for (int f = 0; f < 8; ++f) {
    rn += acc[f][0] * acc[f][0] + acc[f][1] * acc[f][1] +
          acc[f][2] * acc[f][2] + acc[f][3] * acc[f][3];
    ushort4 z4 = {f2bf(acc[f][0]), f2bf(acc[f][1]), f2bf(acc[f][2]), f2bf(acc[f][3])};
    *(ushort4*)(Z + (size_t)(row0 + l15) * HID + f * 16 + lq * 4) = z4;
  }
  rn += __shfl_xor(rn, 16, 64);
  rn += __shfl_xor(rn, 32, 64);
  if (lane < 16) nrm[row0 + l15] = rn;
}

// ---------------- dist: D = n1[i] + n2[j] - 2 * Z1 @ Z2^T ----------------
__global__ __launch_bounds__(256) void k_dist(const unsigned short* __restrict__ Z1b,
                                              const unsigned short* __restrict__ Z2b,
                                              const float* __restrict__ n1,
                                              const float* __restrict__ n2,
                                              float* __restrict__ D, int NY) {
  const int tid = threadIdx.x;
  const int wid = tid >> 6, lane = tid & 63;
  const int wr = wid >> 1, wc = wid & 1;
  const int rowB = blockIdx.y * 128 + wr * 64;
  const int colB = blockIdx.x * 128 + wc * 64;
  const int l15 = lane & 15;
  const int lk = (lane >> 4) * 8;
  const unsigned short* Arow = Z1b + (size_t)(rowB + l15) * HID + lk;
  const unsigned short* Brow = Z2b + (size_t)(colB + l15) * HID + lk;
  f32x4 acc[4][4];
#pragma unroll
  for (int i = 0; i < 4; ++i)
#pragma unroll
    for (int j = 0; j < 4; ++j) acc[i][j] = (f32x4){0.f, 0.f, 0.f, 0.f};
#pragma unroll
  for (int s = 0; s < 4; ++s) {
    bf16x8 a[4], b[4];
#pragma unroll
    for (int i = 0; i < 4; ++i) a[i] = *(const bf16x8*)(Arow + (size_t)i * 16 * HID + s * 32);
#pragma unroll
    for (int j = 0; j < 4; ++j) b[j] = *(const bf16x8*)(Brow + (size_t)j * 16 * HID + s * 32);
#pragma unroll
    for (int i = 0; i < 4; ++i)
#pragma unroll
      for (int j = 0; j < 4; ++j)
        acc[i][j] = __builtin_amdgcn_mfma_f32_16x16x32_bf16(a[i], b[j], acc[i][j], 0, 0, 0);
  }
  float nb[4];
#pragma unroll
  for (int j = 0; j < 4; ++j) nb[j] = n2[colB + j * 16 + l15];
  const int crow0 = (lane >> 4) * 4;
#pragma unroll
  for (int i = 0; i < 4; ++i) {
#pragma unroll
    for (int r = 0; r < 4; ++r) {
      const int row = rowB + i * 16 + crow0 + r;
      const float na = n1[row];
      float* drow = D + (size_t)row * NY + colB + l15;
#pragma unroll
      for (int j = 0; j < 4; ++j)
        drow[j * 16] = na + nb[j] - 2.f * acc[i][j][r];
    }
  }
}

extern "C" void kernel_launch(void* const* d_in, const int* in_sizes, int n_in,
                              void* d_out, int out_size, void* d_ws, size_t ws_size,
                              hipStream_t stream) {
  const float* variations = (const float*)d_in[0];
  const float* exemplar   = (const float*)d_in[1];
  const float* w1         = (const float*)d_in[2];
  const float* gamma      = (const float*)d_in[3];
  const float* beta       = (const float*)d_in[4];
  const float* w2         = (const float*)d_in[5];
  float* D = (float*)d_out;

  const int nx = in_sizes[0] / LAT;  // 8192
  const int ny = in_sizes[1] / LAT;  // 2048
  const int nrows = nx + ny;         // 10240
  const int nbb = nrows / 64;        // 160 blocks
  const int nb1 = nx / 64;           // 128 (set-1 partial blocks)
  const int nb2 = ny / 64;           // 32

  char* p = (char*)d_ws;
  unsigned short* Hb  = (unsigned short*)p; p += (size_t)nrows * HID * 2;  // 2.5 MB
  unsigned short* Zb  = (unsigned short*)p; p += (size_t)nrows * HID * 2;  // 2.5 MB
  unsigned short* W1T = (unsigned short*)p; p += (size_t)LAT * HID * 2;    // 128 KB
  unsigned short* W2T = (unsigned short*)p; p += (size_t)HID * HID * 2;    // 32 KB
  float* pS1 = (float*)p; p += (size_t)nb1 * HID * 4;
  float* pQ1 = (float*)p; p += (size_t)nb1 * HID * 4;
  float* pS2 = (float*)p; p += (size_t)nb2 * HID * 4;
  float* pQ2 = (float*)p; p += (size_t)nb2 * HID * 4;
  float* sc1 = (float*)p; p += HID * 4;
  float* sh1 = (float*)p; p += HID * 4;
  float* sc2 = (float*)p; p += HID * 4;
  float* sh2 = (float*)p; p += HID * 4;
  float* nrmAll = (float*)p; p += (size_t)nrows * 4;
  float* n1v = nrmAll;
  float* n2v = nrmAll + nx;
  unsigned short* Z1b = Zb;
  unsigned short* Z2b = Zb + (size_t)nx * HID;

  k_prep<<<(LAT * HID + HID * HID) / 256, 256, 0, stream>>>(w1, w2, W1T, W2T);
  k_gemm1<<<nbb, 256, 0, stream>>>(variations, exemplar, nx, W1T, Hb,
                                   pS1, pQ1, pS2, pQ2, nb1);
  k_finalize<<<1, 256, 0, stream>>>(pS1, pQ1, pS2, pQ2, gamma, beta,
                                    sc1, sh1, sc2, sh2, nb1, nb2, (float)nx, (float)ny);
  k_gemm2<<<nbb, 256, 0, stream>>>(Hb, nx, W2T, sc1, sh1, sc2, sh2, Zb, nrmAll);
  dim3 dgrid(ny / 128, nx / 128);
  k_dist<<<dgrid, 256, 0, stream>>>(Z1b, Z2b, n1v, n2v, D, ny);
}